// Round 7
// baseline (278.641 us; speedup 1.0000x reference)
//
#include <hip/hip_runtime.h>

// MAUCHLoss: B=2097152 rows, C=15 categories, f32 inputs.
//
// R14 = R13 resubmitted verbatim (R13 bench was an infra failure:
// "MI355X container failed twice" — no counters, hypothesis untested).
//
// R13: probe = NT loads x 8 waves/SIMD (the one untested combination).
// Session knowledge baked in:
//  - NT (__builtin_nontemporal_load) is mandatory: cached loads run
//    1.2-2.3 TB/s vs NT 4.6 TB/s (R8-R12 A/B across 4 structures).
//  - FULL unroll of a register ring lets SSA renaming delete the WAR
//    deps -> scheduler builds a max-depth pipeline and spills (R9:
//    81MB scratch writes). A runtime back-edge every PF iters keeps
//    the window bounded (R11: no spill). VGPR_Count in the counter CSV
//    is junk (reported 32 for 4 different kernels incl. unbounded).
//  - Partial-store epilogue + wide final costs +12.7us vs round-0's
//    memset+atomics+tiny-final (R12 263.9 vs R0 251.2). Reverted here.
// This round's single variable: PF=2 ring (live ~47 VGPR) +
// __launch_bounds__(256,8) + 1920 blocks (=15*2^15/256, category
// phase constant per thread; ~7.5 blocks/CU at 8 waves/SIMD), ITERS=16.
// Steady loop = 14 iters, unroll 2 (i%2 compile-time), peeled 2-iter
// tail. Diagnosis if it fails: WRITE_SIZE>=50MB -> allocator over-cap,
// revert to R12-main + this epilogue; main ~55us & no spill -> 4.6 TB/s
// is the NT-path ceiling -> roofline.

#define CATS 15
#define NBLOCKS 1920  // 1920*256*4 = 1,966,080 = 15*131072 -> phase constant
#define NTHREADS 256
#define NSUMS (3 * CATS + 1)   // 46
#define PF 2                   // ring depth: 4 loads in flight per wave
#define ITERS 16               // nFloat4 / stride for the fixed problem size

typedef float vf4 __attribute__((ext_vector_type(4)));

__device__ __forceinline__ vf4 ntload4(const vf4* p) {
    return __builtin_nontemporal_load(p);
}

// softplus(-s) = log(1+exp(-s)) on s in (0,1): degree-4 poly, |err| < 1e-4.
__device__ __forceinline__ float softplus_neg_unit(float s) {
    const float c0 = 0.69314718f, c1 = -0.5f, c2 = 0.125f, c4 = -0.0048853f;
    float s2 = s * s;
    return c0 + fmaf(c1, s, fmaf(c2, s2, c4 * s2 * s2));
}

__device__ __forceinline__ void accum_elem(float x, float l,
                                           float& ssig, float& spos, float& snp,
                                           float& scel) {
    float e   = __expf(-x);                       // transcendental 1
    float sig = __builtin_amdgcn_rcpf(1.0f + e);  // transcendental 2
    ssig += sig;
    spos = fmaf(sig, l, spos);
    snp  += l;
    scel += softplus_neg_unit(sig);
}

__global__ __launch_bounds__(NTHREADS, 8) void mauch_main(
    const float* __restrict__ outp, const float* __restrict__ labp,
    float* __restrict__ ws, int nFloat4)
{
    const int t = blockIdx.x * blockDim.x + threadIdx.x;
    const int stride = gridDim.x * blockDim.x;   // stride*4 % 15 == 0

    float ssig[4] = {0.f, 0.f, 0.f, 0.f};
    float spos[4] = {0.f, 0.f, 0.f, 0.f};
    float snp[4]  = {0.f, 0.f, 0.f, 0.f};
    float scel = 0.f;

    const vf4* o4 = (const vf4*)outp;
    const vf4* l4 = (const vf4*)labp;

    if (nFloat4 == ITERS * stride) {
        // PF=2 register ring. Runtime back-edge every 2 iters keeps the
        // WAR deps real -> scheduler window stays at 4 loads (~47 VGPR
        // live), fits the 64-VGPR / 8-wave budget without spilling.
        vf4 ob[PF], lb[PF];
#pragma unroll
        for (int p = 0; p < PF; ++p) {
            ob[p] = ntload4(o4 + t + p * stride);
            lb[p] = ntload4(l4 + t + p * stride);
        }
        // steady state: i = 0 .. ITERS-PF-1 (14 iters, divisible by 2;
        // i%2 is compile-time inside the unroll-2 body)
#pragma unroll 2
        for (int i = 0; i < ITERS - PF; ++i) {
            vf4 ov = ob[i & 1];
            vf4 lv = lb[i & 1];
            ob[i & 1] = ntload4(o4 + t + (i + PF) * stride);
            lb[i & 1] = ntload4(l4 + t + (i + PF) * stride);
#pragma unroll
            for (int j = 0; j < 4; ++j)
                accum_elem(ov[j], lv[j], ssig[j], spos[j], snp[j], scel);
        }
        // peeled tail: drain the ring (constant slot indices)
#pragma unroll
        for (int i = ITERS - PF; i < ITERS; ++i) {
            vf4 ov = ob[i & 1];
            vf4 lv = lb[i & 1];
#pragma unroll
            for (int j = 0; j < 4; ++j)
                accum_elem(ov[j], lv[j], ssig[j], spos[j], snp[j], scel);
        }
    } else {
#pragma unroll 1
        for (int f = t; f < nFloat4; f += stride) {
            vf4 ov = ntload4(o4 + f);
            vf4 lv = ntload4(l4 + f);
#pragma unroll
            for (int j = 0; j < 4; ++j)
                accum_elem(ov[j], lv[j], ssig[j], spos[j], snp[j], scel);
        }
    }

    // ---- block reduction in LDS ----
    __shared__ float red[NSUMS];
    for (int i = threadIdx.x; i < NSUMS; i += blockDim.x) red[i] = 0.f;
    __syncthreads();

    // element categories for this thread: (4t + j) mod 15, constant across iterations
    int base = (4 * t) % CATS;
#pragma unroll
    for (int j = 0; j < 4; ++j) {
        int c = base + j; if (c >= CATS) c -= CATS;
        atomicAdd(&red[c],            ssig[j]);
        atomicAdd(&red[CATS + c],     spos[j]);
        atomicAdd(&red[2 * CATS + c], snp[j]);
    }
    atomicAdd(&red[3 * CATS], scel);
    __syncthreads();

    // ---- global accumulation (device-scope atomics) — round-0 epilogue ----
    if (threadIdx.x < NSUMS) atomicAdd(&ws[threadIdx.x], red[threadIdx.x]);
}

__global__ void mauch_final(const float* __restrict__ ws, float* __restrict__ out,
                            float invBC, float rowsB)
{
    if (threadIdx.x == 0 && blockIdx.x == 0) {
        float sum_term = 0.f, pen_last = 0.f;
        float tot_ssig = 0.f, tot_spos = 0.f;
#pragma unroll
        for (int c = 0; c < CATS; ++c) {
            float ssig = ws[c];
            float sp   = ws[CATS + c];
            float np   = ws[2 * CATS + c];
            float nn   = rowsB - np;
            float sneg = ssig - sp;
            tot_ssig += ssig;
            tot_spos += sp;
            float mp = (np > 0.f) ? sp   / fmaxf(np, 1.f) : 0.f;
            float mn = (nn > 0.f) ? sneg / fmaxf(nn, 1.f) : 0.f;
            float pen = 1.f - mp + mn;
            sum_term += pen;
            if (c == CATS - 1) pen_last = pen;
        }
        // cel = mean(sp + (1-l)*sig); sum((1-l)*sig) = sum(sig) - sum(sig*l)
        float cel = (ws[3 * CATS] + (tot_ssig - tot_spos)) * invBC;
        out[0] = cel + 0.1f * (sum_term / 15.f);
        out[1] = 0.1f * pen_last;
    }
}

extern "C" void kernel_launch(void* const* d_in, const int* in_sizes, int n_in,
                              void* d_out, int out_size, void* d_ws, size_t ws_size,
                              hipStream_t stream) {
    const float* outp = (const float*)d_in[0];
    const float* labp = (const float*)d_in[1];
    float* out = (float*)d_out;
    float* ws  = (float*)d_ws;

    const int total   = in_sizes[0];          // B * 15
    const int nFloat4 = total / 4;
    const float rowsB = (float)(total / CATS);
    const float invBC = 1.0f / (float)total;

    // ws is re-poisoned before every timed launch -> zero it (capture-safe async memset)
    hipMemsetAsync(ws, 0, NSUMS * sizeof(float), stream);

    mauch_main<<<NBLOCKS, NTHREADS, 0, stream>>>(outp, labp, ws, nFloat4);
    mauch_final<<<1, 64, 0, stream>>>(ws, out, invBC, rowsB);
}

// Round 8
// 250.917 us; speedup vs baseline: 1.1105x; 1.1105x over previous
//
#include <hip/hip_runtime.h>

// MAUCHLoss: B=2097152 rows, C=15 categories, f32 inputs.
// ws layout (46 floats): [0..14] sum(sig) per cat, [15..29] sum(sig*label),
// [30..44] sum(label) (npos), [45] sum(softplus(-sig)) for CEL.
//
// R15: REVERT to session-best anchor (round-0 kernel, 248.7us prior
// session / 251.2us round-0). Session ledger on the main kernel:
//  - NT loads are mandatory: cached paths run 1.2-3.3 TB/s vs NT 4.6
//    (R8-R14, A/B across 5 structures).
//  - Per-wave MLP depth (PF=8-10 ring, ~112 VGPR, 4 waves/SIMD) beats
//    every occupancy-first variant: R14 (PF=2, 8-wave bound, no spill,
//    WRITE 360B) ran 77.6us vs anchor 55us -> the compiler serializes
//    shallow rings to fit the reg budget, killing MLP. TLP theory dead.
//  - Full unroll of a ring + min-waves bound = SSA renaming deletes WAR
//    deps -> spill storm (R9: 81MB scratch writes). Don't combine.
//  - Partial-store epilogue + wide final: +12.7us vs memset+atomics
//    (R12). Round-0 epilogue restored.
// Remaining dur_us (~196us) is harness-fixed: 503MB ws poison fill at
// 6.8-6.9 TB/s (HBM write roofline) + restores. Main at 4.6 TB/s is the
// measured NT-path plateau for this pattern; 7 probes to exceed it all
// regressed.

#define CATS 15
#define NBLOCKS 960   // 960*256*4 = 983,040 = 15*65536 -> category phase constant per thread
#define NTHREADS 256
#define NSUMS (3 * CATS + 1)   // 46
#define PF 10                  // pipeline depth (iterations ahead)
#define ITERS 32               // nFloat4 / stride for the fixed problem size

typedef float vf4 __attribute__((ext_vector_type(4)));

__device__ __forceinline__ vf4 ntload4(const vf4* p) {
    return __builtin_nontemporal_load(p);
}

// softplus(-s) = log(1+exp(-s)) on s in (0,1): degree-4 poly, |err| < 1e-4.
__device__ __forceinline__ float softplus_neg_unit(float s) {
    const float c0 = 0.69314718f, c1 = -0.5f, c2 = 0.125f, c4 = -0.0048853f;
    float s2 = s * s;
    return c0 + fmaf(c1, s, fmaf(c2, s2, c4 * s2 * s2));
}

__device__ __forceinline__ void accum_elem(float x, float l,
                                           float& ssig, float& spos, float& snp,
                                           float& scel) {
    float e   = __expf(-x);                       // transcendental 1
    float sig = __builtin_amdgcn_rcpf(1.0f + e);  // transcendental 2
    ssig += sig;
    spos = fmaf(sig, l, spos);
    snp  += l;
    scel += softplus_neg_unit(sig);
}

__global__ __launch_bounds__(NTHREADS) void mauch_main(
    const float* __restrict__ outp, const float* __restrict__ labp,
    float* __restrict__ ws, int nFloat4)
{
    const int t = blockIdx.x * blockDim.x + threadIdx.x;
    const int stride = gridDim.x * blockDim.x;   // stride*4 % 15 == 0

    float ssig[4] = {0.f, 0.f, 0.f, 0.f};
    float spos[4] = {0.f, 0.f, 0.f, 0.f};
    float snp[4]  = {0.f, 0.f, 0.f, 0.f};
    float scel = 0.f;

    const vf4* o4 = (const vf4*)outp;
    const vf4* l4 = (const vf4*)labp;

    if (nFloat4 == ITERS * stride) {
        // fixed-size fast path: explicit PF-deep register pipeline
        vf4 ob[PF], lb[PF];
#pragma unroll
        for (int p = 0; p < PF; ++p) {
            ob[p] = ntload4(o4 + t + p * stride);
            lb[p] = ntload4(l4 + t + p * stride);
        }
#pragma unroll
        for (int i = 0; i < ITERS; ++i) {
            vf4 ov = ob[i % PF];
            vf4 lv = lb[i % PF];
            if (i + PF < ITERS) {
                ob[i % PF] = ntload4(o4 + t + (i + PF) * stride);
                lb[i % PF] = ntload4(l4 + t + (i + PF) * stride);
            }
#pragma unroll
            for (int j = 0; j < 4; ++j)
                accum_elem(ov[j], lv[j], ssig[j], spos[j], snp[j], scel);
        }
    } else {
        for (int f = t; f < nFloat4; f += stride) {
            vf4 ov = ntload4(o4 + f);
            vf4 lv = ntload4(l4 + f);
#pragma unroll
            for (int j = 0; j < 4; ++j)
                accum_elem(ov[j], lv[j], ssig[j], spos[j], snp[j], scel);
        }
    }

    // ---- block reduction in LDS ----
    __shared__ float red[NSUMS];
    for (int i = threadIdx.x; i < NSUMS; i += blockDim.x) red[i] = 0.f;
    __syncthreads();

    // element categories for this thread: (4t + j) mod 15, constant across iterations
    int base = (4 * t) % CATS;
#pragma unroll
    for (int j = 0; j < 4; ++j) {
        int c = base + j; if (c >= CATS) c -= CATS;
        atomicAdd(&red[c],            ssig[j]);
        atomicAdd(&red[CATS + c],     spos[j]);
        atomicAdd(&red[2 * CATS + c], snp[j]);
    }
    atomicAdd(&red[3 * CATS], scel);
    __syncthreads();

    // ---- global accumulation (device-scope atomics, no fence) ----
    if (threadIdx.x < NSUMS) atomicAdd(&ws[threadIdx.x], red[threadIdx.x]);
}

__global__ void mauch_final(const float* __restrict__ ws, float* __restrict__ out,
                            float invBC, float rowsB)
{
    if (threadIdx.x == 0 && blockIdx.x == 0) {
        float sum_term = 0.f, pen_last = 0.f;
        float tot_ssig = 0.f, tot_spos = 0.f;
#pragma unroll
        for (int c = 0; c < CATS; ++c) {
            float ssig = ws[c];
            float sp   = ws[CATS + c];
            float np   = ws[2 * CATS + c];
            float nn   = rowsB - np;
            float sneg = ssig - sp;
            tot_ssig += ssig;
            tot_spos += sp;
            float mp = (np > 0.f) ? sp   / fmaxf(np, 1.f) : 0.f;
            float mn = (nn > 0.f) ? sneg / fmaxf(nn, 1.f) : 0.f;
            float pen = 1.f - mp + mn;
            sum_term += pen;
            if (c == CATS - 1) pen_last = pen;
        }
        // cel = mean(sp + (1-l)*sig); sum((1-l)*sig) = sum(sig) - sum(sig*l)
        float cel = (ws[3 * CATS] + (tot_ssig - tot_spos)) * invBC;
        out[0] = cel + 0.1f * (sum_term / 15.f);
        out[1] = 0.1f * pen_last;
    }
}

extern "C" void kernel_launch(void* const* d_in, const int* in_sizes, int n_in,
                              void* d_out, int out_size, void* d_ws, size_t ws_size,
                              hipStream_t stream) {
    const float* outp = (const float*)d_in[0];
    const float* labp = (const float*)d_in[1];
    float* out = (float*)d_out;
    float* ws  = (float*)d_ws;

    const int total   = in_sizes[0];          // B * 15
    const int nFloat4 = total / 4;
    const float rowsB = (float)(total / CATS);
    const float invBC = 1.0f / (float)total;

    // ws is re-poisoned before every timed launch -> zero it (capture-safe async memset)
    hipMemsetAsync(ws, 0, NSUMS * sizeof(float), stream);

    mauch_main<<<NBLOCKS, NTHREADS, 0, stream>>>(outp, labp, ws, nFloat4);
    mauch_final<<<1, 64, 0, stream>>>(ws, out, invBC, rowsB);
}